// Round 1
// baseline (1796.646 us; speedup 1.0000x reference)
//
#include <hip/hip_runtime.h>
#include <math.h>

#define NB 16
#define NH 16
#define DD 2048
#define DKK 128
#define LL 4096
#define NCH 8      // L chunks per (b,h)
#define CHK 512    // LL / NCH
#define SCALE 0.08838834764831844f  // 1/sqrt(128)

// ws layout (floats):
// [0,      32768)   Q        [b*2048 + h*128 + dk]
// [32768,  65536)   K_new
// [65536,  98304)   V_new
// [98304, 131072)   attn
// [131072,133120)   m partials   [bh*8 + chunk]
// [133120,135168)   l partials
// [135168,397312)   acc partials [ (bh*8+chunk)*128 + dk ]

__global__ void init_qkv(const float* __restrict__ bq, const float* __restrict__ bk,
                         const float* __restrict__ bv, float* __restrict__ ws) {
    int idx = blockIdx.x * 256 + threadIdx.x;   // 98304 total
    int w = idx >> 15;
    int j = idx & 2047;
    const float* b = (w == 0) ? bq : (w == 1) ? bk : bv;
    ws[idx] = b[j];
}

// Q/K/V projections: dst[b][j] += sum_i x[b][i] * W[i][j]
// grid (8 jtiles, 16 ktiles, 3 weights), block 256. Weight read once; 16 batch
// accumulators in registers; split-K combined via atomicAdd (ws pre-seeded with bias).
__global__ void proj_qkv(const float* __restrict__ x,
                         const float* __restrict__ Wq,
                         const float* __restrict__ Wk,
                         const float* __restrict__ Wv,
                         float* __restrict__ ws) {
    const int tid = threadIdx.x;
    const int j = blockIdx.x * 256 + tid;
    const int i0 = blockIdx.y * 128;
    const int w = blockIdx.z;
    const float* __restrict__ W = (w == 0) ? Wq : (w == 1) ? Wk : Wv;
    float* dst = ws + w * (NB * DD);
    __shared__ float xs[NB * 128];
    for (int t = tid; t < NB * 128; t += 256) {
        int b = t >> 7, ii = t & 127;
        xs[t] = x[b * DD + i0 + ii];
    }
    __syncthreads();
    float acc[NB];
#pragma unroll
    for (int b = 0; b < NB; ++b) acc[b] = 0.f;
    for (int ii = 0; ii < 128; ++ii) {
        float wv = W[(size_t)(i0 + ii) * DD + j];
#pragma unroll
        for (int b = 0; b < NB; ++b) acc[b] += xs[b * 128 + ii] * wv;
    }
#pragma unroll
    for (int b = 0; b < NB; ++b) atomicAdd(&dst[b * DD + j], acc[b]);
}

// Fused cache-copy + split-K attention partial.
// grid (8 chunks, 16 h, 16 b), block 256 (8 rows x 32 lanes per iteration).
__global__ void attn_partial(const float* __restrict__ cache_k,
                             const float* __restrict__ cache_v,
                             const float* __restrict__ ws,
                             float* __restrict__ koutBase, float* __restrict__ voutBase,
                             float* __restrict__ m_ws, float* __restrict__ l_ws,
                             float* __restrict__ acc_ws) {
    const int tid = threadIdx.x;
    const int chunk = blockIdx.x;
    const int h = blockIdx.y;
    const int b = blockIdx.z;
    const int bh = b * NH + h;
    const int lane = tid & 31;
    const int r = tid >> 5;           // 0..7
    const int c0 = chunk * CHK;

    __shared__ float sc[CHK];         // scores, then probs
    __shared__ float red[256];
    __shared__ float accs[8 * DKK];

    // Per-thread Q fragment (dk = lane*4 .. +3), constant across iterations.
    const float4 q4 = ((const float4*)(ws + bh * DKK))[lane];

    const float4* kin  = (const float4*)cache_k + (size_t)(bh * LL + c0) * 32;
    float4*       kout = (float4*)koutBase      + (size_t)(bh * 4097 + c0) * 32;

    // K pass: copy cache_k -> out K while computing scores.
    for (int it = 0; it < CHK / 8; ++it) {
        int jloc = it * 8 + r;
        float4 kk = kin[jloc * 32 + lane];
        kout[jloc * 32 + lane] = kk;
        float d = kk.x * q4.x + kk.y * q4.y + kk.z * q4.z + kk.w * q4.w;
#pragma unroll
        for (int m = 16; m >= 1; m >>= 1) d += __shfl_xor(d, m);
        if (lane == 0) sc[jloc] = d * SCALE;
    }
    __syncthreads();

    // chunk max
    float mv = fmaxf(sc[tid], sc[tid + 256]);
    red[tid] = mv;
    __syncthreads();
    for (int off = 128; off > 0; off >>= 1) {
        if (tid < off) red[tid] = fmaxf(red[tid], red[tid + off]);
        __syncthreads();
    }
    const float M = red[0];
    __syncthreads();

    // probs + chunk sumexp
    float p0 = __expf(sc[tid] - M), p1 = __expf(sc[tid + 256] - M);
    sc[tid] = p0; sc[tid + 256] = p1;
    red[tid] = p0 + p1;
    __syncthreads();
    for (int off = 128; off > 0; off >>= 1) {
        if (tid < off) red[tid] += red[tid + off];
        __syncthreads();
    }
    const float lsum = red[0];

    // V pass: copy cache_v -> out V while accumulating p * V.
    const float4* vin  = (const float4*)cache_v + (size_t)(bh * LL + c0) * 32;
    float4*       vout = (float4*)voutBase      + (size_t)(bh * 4097 + c0) * 32;
    float4 acc4 = {0.f, 0.f, 0.f, 0.f};
    for (int it = 0; it < CHK / 8; ++it) {
        int jloc = it * 8 + r;
        float4 vv = vin[jloc * 32 + lane];
        vout[jloc * 32 + lane] = vv;
        float p = sc[jloc];
        acc4.x += p * vv.x; acc4.y += p * vv.y; acc4.z += p * vv.z; acc4.w += p * vv.w;
    }
    ((float4*)accs)[r * 32 + lane] = acc4;
    __syncthreads();
    if (tid < DKK) {
        float a = 0.f;
#pragma unroll
        for (int g = 0; g < 8; ++g) a += accs[g * DKK + tid];
        acc_ws[(bh * NCH + chunk) * DKK + tid] = a;
    }
    if (tid == 0) {
        m_ws[bh * NCH + chunk] = M;
        l_ws[bh * NCH + chunk] = lsum;
    }
}

// Merge partials + new-token K/V row + write attn; also bias-init `out`.
// grid 256 (bh), block 128.
__global__ void attn_combine(const float* __restrict__ ws, const float* __restrict__ bo,
                             float* __restrict__ outBase, float* __restrict__ koutBase,
                             float* __restrict__ voutBase,
                             const float* __restrict__ m_ws, const float* __restrict__ l_ws,
                             const float* __restrict__ acc_ws, float* __restrict__ attn_ws) {
    const int bh = blockIdx.x;
    const int t = threadIdx.x;  // 0..127
    const float* qws = ws;
    const float* kws = ws + 32768;
    const float* vws = ws + 65536;

    float kn = kws[bh * DKK + t];
    float vn = vws[bh * DKK + t];
    koutBase[(size_t)(bh * 4097 + LL) * DKK + t] = kn;
    voutBase[(size_t)(bh * 4097 + LL) * DKK + t] = vn;

    // s_new = Q . K_new * scale (block reduce over 128 threads = 2 waves)
    float d = qws[bh * DKK + t] * kn;
#pragma unroll
    for (int m = 32; m >= 1; m >>= 1) d += __shfl_xor(d, m);
    __shared__ float sd[2];
    if ((t & 63) == 0) sd[t >> 6] = d;
    __syncthreads();
    const float snew = (sd[0] + sd[1]) * SCALE;

    float M = snew;
    float mc[NCH];
#pragma unroll
    for (int c = 0; c < NCH; ++c) { mc[c] = m_ws[bh * NCH + c]; M = fmaxf(M, mc[c]); }
    float wnew = __expf(snew - M);
    float lsum = wnew;
    float av = wnew * vn;
#pragma unroll
    for (int c = 0; c < NCH; ++c) {
        float wc = __expf(mc[c] - M);
        lsum += l_ws[bh * NCH + c] * wc;
        av += acc_ws[(bh * NCH + c) * DKK + t] * wc;
    }
    attn_ws[bh * DKK + t] = av / lsum;

    // out[b][h*128+t] flat-linearizes to bh*128+t: seed with bias for out_proj atomics.
    outBase[bh * DKK + t] = bo[(bh & (NH - 1)) * DKK + t];
}

// out[b][j] += sum_i attn[b][i] * Wo[i][j]; grid (8 jtiles, 16 ktiles), block 256.
__global__ void out_proj(const float* __restrict__ attn_ws, const float* __restrict__ Wo,
                         float* __restrict__ outBase) {
    const int tid = threadIdx.x;
    const int j = blockIdx.x * 256 + tid;
    const int i0 = blockIdx.y * 128;
    __shared__ float xs[NB * 128];
    for (int t = tid; t < NB * 128; t += 256) {
        int b = t >> 7, ii = t & 127;
        xs[t] = attn_ws[b * DD + i0 + ii];
    }
    __syncthreads();
    float acc[NB];
#pragma unroll
    for (int b = 0; b < NB; ++b) acc[b] = 0.f;
    for (int ii = 0; ii < 128; ++ii) {
        float wv = Wo[(size_t)(i0 + ii) * DD + j];
#pragma unroll
        for (int b = 0; b < NB; ++b) acc[b] += xs[b * 128 + ii] * wv;
    }
#pragma unroll
    for (int b = 0; b < NB; ++b) atomicAdd(&outBase[b * DD + j], acc[b]);
}

extern "C" void kernel_launch(void* const* d_in, const int* in_sizes, int n_in,
                              void* d_out, int out_size, void* d_ws, size_t ws_size,
                              hipStream_t stream) {
    const float* x       = (const float*)d_in[0];
    const float* cache_k = (const float*)d_in[1];
    const float* cache_v = (const float*)d_in[2];
    const float* Wq      = (const float*)d_in[3];
    const float* bq      = (const float*)d_in[4];
    const float* Wk      = (const float*)d_in[5];
    const float* bk      = (const float*)d_in[6];
    const float* Wv      = (const float*)d_in[7];
    const float* bv      = (const float*)d_in[8];
    const float* Wo      = (const float*)d_in[9];
    const float* bo      = (const float*)d_in[10];

    float* out  = (float*)d_out;                       // (16,1,2048)
    float* kout = out + (size_t)NB * DD;               // (16,16,4097,128)
    float* vout = kout + (size_t)NB * NH * 4097 * DKK; // (16,16,4097,128)

    float* ws      = (float*)d_ws;
    float* attn_ws = ws + 98304;
    float* m_ws    = ws + 131072;
    float* l_ws    = ws + 133120;
    float* acc_ws  = ws + 135168;

    hipLaunchKernelGGL(init_qkv, dim3(384), dim3(256), 0, stream, bq, bk, bv, ws);
    hipLaunchKernelGGL(proj_qkv, dim3(8, 16, 3), dim3(256), 0, stream, x, Wq, Wk, Wv, ws);
    hipLaunchKernelGGL(attn_partial, dim3(NCH, NH, NB), dim3(256), 0, stream,
                       cache_k, cache_v, ws, kout, vout, m_ws, l_ws, acc_ws);
    hipLaunchKernelGGL(attn_combine, dim3(256), dim3(128), 0, stream,
                       ws, bo, out, kout, vout, m_ws, l_ws, acc_ws, attn_ws);
    hipLaunchKernelGGL(out_proj, dim3(8, 16), dim3(256), 0, stream, attn_ws, Wo, out);
}